// Round 4
// baseline (265.101 us; speedup 1.0000x reference)
//
#include <hip/hip_runtime.h>
#include <stdint.h>

typedef unsigned short u16;
typedef unsigned int u32;
typedef float f32x4 __attribute__((ext_vector_type(4)));
typedef __bf16 bf16x8 __attribute__((ext_vector_type(8)));

#define BS 2
#define SEQ 2048
#define DIM 1024
#define NW3 3072
#define NH 16
#define HD 64

#define MFMA_BF16(a, b, c) __builtin_amdgcn_mfma_f32_16x16x32_bf16((a), (b), (c), 0, 0, 0)

// async global->LDS, 16B per lane; LDS dest must be wave-uniform base + lane*16
#define GLL16(g, l)                                                                \
  __builtin_amdgcn_global_load_lds(                                                \
      (__attribute__((address_space(1))) void*)(void*)(uintptr_t)(g),              \
      (__attribute__((address_space(3))) void*)(l), 16, 0, 0)

__device__ __forceinline__ float fexp2(float x) {
#if defined(__has_builtin)
#if __has_builtin(__builtin_amdgcn_exp2f)
  return __builtin_amdgcn_exp2f(x);
#else
  return exp2f(x);
#endif
#else
  return exp2f(x);
#endif
}

__device__ __forceinline__ u16 f2bf(float x) {
  __bf16 h = (__bf16)x;
  return __builtin_bit_cast(u16, h);
}

// ---------------- fp32 -> bf16 straight convert (embeddings) ----------------
__global__ __launch_bounds__(256) void conv_a_kernel(const float* __restrict__ A,
                                                     u16* __restrict__ O) {
  int i = (blockIdx.x * 256 + threadIdx.x) * 4;
  float4 v = *(const float4*)(A + i);
  union { u16 u[4]; ushort4 v4; } p;
  p.u[0] = f2bf(v.x); p.u[1] = f2bf(v.y); p.u[2] = f2bf(v.z); p.u[3] = f2bf(v.w);
  *(ushort4*)(O + i) = p.v4;
}

// ---------------- W [k][n] fp32 -> Wt [n'][k] bf16 (transposed + head-permuted) --
// Output ROW n' is head-grouped: n' = which*1024 + h*64 + hd  where the original
// column n = which*1024 + hd*16 + h. GEMM output columns then come out in
// (which, h, hd) order -> dense epilogue stores.
__global__ __launch_bounds__(256) void conv_wt_kernel(const float* __restrict__ W,
                                                      u16* __restrict__ Wt) {
  int id = blockIdx.x * 256 + threadIdx.x;  // 0 .. 393215
  int kc = id / NW3;                        // 0..127 : chunk of 8 k's
  int n = id - kc * NW3;                    // original column; lanes consecutive -> coalesced reads
  union { u16 u[8]; uint4 v; } p;
#pragma unroll
  for (int i = 0; i < 8; ++i) p.u[i] = f2bf(W[(kc * 8 + i) * NW3 + n]);
  int h = n & 15, hd = (n & 1023) >> 4;
  int np = (n & ~1023) + h * 64 + hd;       // permuted row
  *(uint4*)(Wt + np * DIM + kc * 8) = p.v;
}

// ---------------- QKV GEMM: [4096x1024]x[1024x3072]+b, bf16 MFMA ----------------
// 128x128 tile, BK=64, global_load_lds w/ XOR-swizzled 16B chunks.
// Columns are head-grouped (see conv_wt), so epilogue stores are dense:
// Q/K -> [b,h,s,hd] (32B segments per quad-row), V -> [b,h,hd,s] (uint2 along s).
__global__ __launch_bounds__(256) void gemm_qkv_kernel(
    const u16* __restrict__ Ab, const u16* __restrict__ Bt, const float* __restrict__ bias,
    u16* __restrict__ Q, u16* __restrict__ K, u16* __restrict__ Vt) {
  __shared__ __align__(16) u16 Al[128 * 64];
  __shared__ __align__(16) u16 Bl[128 * 64];
  const int t = threadIdx.x;
  const int lane = t & 63, wave = t >> 6;
  const int c = lane & 15, quad = lane >> 4;
  const int tm = blockIdx.x / 24, tn = blockIdx.x - tm * 24;
  const int wm = (wave >> 1) * 64, wn = (wave & 1) * 64;

  const char* Abase = (const char*)(Ab + (size_t)tm * 128 * DIM);
  const char* Bbase = (const char*)(Bt + (size_t)tn * 128 * DIM);

  f32x4 z = {0.f, 0.f, 0.f, 0.f};
  f32x4 acc[4][4];
#pragma unroll
  for (int i = 0; i < 4; ++i)
#pragma unroll
    for (int j = 0; j < 4; ++j) acc[i][j] = z;

  for (int kt = 0; kt < 16; ++kt) {
    __syncthreads();
    const int koff = kt * 128;  // byte offset of k0 within a row
#pragma unroll
    for (int r = 0; r < 4; ++r) {
      int l = r * 256 + t;          // 16B chunk id, wave-contiguous
      int row = l >> 3, pos = l & 7;
      int kc = pos ^ (row & 7);     // XOR swizzle (global side)
      GLL16(Abase + row * 2048 + koff + kc * 16, (char*)Al + l * 16);
      GLL16(Bbase + row * 2048 + koff + kc * 16, (char*)Bl + l * 16);
    }
    __syncthreads();
#pragma unroll
    for (int ks = 0; ks < 2; ++ks) {
      bf16x8 af[4], bfr[4];
#pragma unroll
      for (int mt = 0; mt < 4; ++mt) {
        int row = wm + mt * 16 + c;
        int kc = (ks * 4 + quad) ^ (row & 7);
        af[mt] = *(const bf16x8*)((const char*)Al + row * 128 + kc * 16);
      }
#pragma unroll
      for (int nt = 0; nt < 4; ++nt) {
        int row = wn + nt * 16 + c;
        int kc = (ks * 4 + quad) ^ (row & 7);
        bfr[nt] = *(const bf16x8*)((const char*)Bl + row * 128 + kc * 16);
      }
#pragma unroll
      for (int mt = 0; mt < 4; ++mt)
#pragma unroll
        for (int nt = 0; nt < 4; ++nt)
          acc[mt][nt] = MFMA_BF16(af[mt], bfr[nt], acc[mt][nt]);
    }
  }

  // Epilogue: C/D layout col = lane&15, row = quad*4 + reg (m89-verified).
  // Permuted column np: which = np>>10, h = (np&1023)>>6, hd = np&63.
#pragma unroll
  for (int nt = 0; nt < 4; ++nt) {
    int np = tn * 128 + wn + nt * 16 + c;
    int which = np >> 10;           // wave-uniform (128-col tile within one of Q/K/V)
    int rem = np & 1023;
    int h = rem >> 6, hd = rem & 63;
    float bv = bias[(np & ~1023) + hd * 16 + h];  // bias is in ORIGINAL column order
#pragma unroll
    for (int mt = 0; mt < 4; ++mt) {
      int mbase = tm * 128 + wm + mt * 16 + quad * 4;
      int bI = mbase >> 11;
      int s0 = mbase & 2047;
      if (which == 2) {
        union { u16 u[4]; uint2 v; } p;
#pragma unroll
        for (int r = 0; r < 4; ++r) p.u[r] = f2bf(acc[mt][nt][r] + bv);
        *(uint2*)(Vt + ((size_t)(bI * NH + h) * HD + hd) * SEQ + s0) = p.v;  // [b,h,hd,s]
      } else {
        u16* dst = (which == 0) ? Q : K;
#pragma unroll
        for (int r = 0; r < 4; ++r)
          dst[((size_t)(bI * NH + h) * SEQ + (s0 + r)) * HD + hd] = f2bf(acc[mt][nt][r] + bv);
      }
    }
  }
}

// ---------------- Flash attention v3: BARRIER-FREE, wave-autonomous ----------------
// R2/R3 lesson: block-wide barriers force vmcnt(0) drains the compiler places
// wherever it wants — per-iteration barriers make the kernel stall-bound (131 µs
// at 10% MfmaUtil). Fix: no __syncthreads at all. Each wave owns a 32-q-row
// stripe and loads K/V/Q fragments DIRECTLY from global in MFMA operand layout
// (lane (c,quad) reads 16 contiguous bytes). LDS is only the per-wave P
// roundtrip (C-layout -> B-frag transform), ordered by same-wave lgkmcnt.
// A-frag: lane holds A[m = lane&15][k = quad*8 + j]   (m118/m120-verified)
// B-frag: lane holds B[k = quad*8 + j][n = lane&15]
#define CSC 0.18033688011112042f  // 0.125 * log2(e)

__global__ __launch_bounds__(256, 2) void attn_kernel(
    const u16* __restrict__ Q, const u16* __restrict__ K,
    const u16* __restrict__ Vt, float* __restrict__ Out) {
  __shared__ __align__(16) char Pl[4 * 32 * 256];  // 32 KB, per-wave P [s_q][s_k]
  const int t = threadIdx.x;
  const int lane = t & 63, wave = t >> 6;
  const int c = lane & 15, quad = lane >> 4;
  const int qt = blockIdx.x & 15, bh = blockIdx.x >> 4;
  const int h = bh & 15, b = bh >> 4;

  // per-lane fragment base pointers
  const char* Qc = (const char*)(Q + ((size_t)bh * SEQ + qt * 128 + wave * 32) * HD)
                   + c * 128 + quad * 16;
  const char* Kc = (const char*)(K + (size_t)bh * SEQ * HD) + c * 128 + quad * 16;
  const char* Vc = (const char*)(Vt + (size_t)bh * HD * SEQ) + c * 4096 + quad * 16;

  // Q B-frags (held in registers whole kernel): Q[s_q = stripe+nt*16+c][hd = ks*32+quad*8+j]
  bf16x8 qf[2][2];
#pragma unroll
  for (int nt = 0; nt < 2; ++nt)
#pragma unroll
    for (int ks = 0; ks < 2; ++ks)
      qf[nt][ks] = *(const bf16x8*)(Qc + nt * 2048 + ks * 64);

  float mM[2] = {-__builtin_inff(), -__builtin_inff()};
  float lS[2] = {0.f, 0.f};
  f32x4 z = {0.f, 0.f, 0.f, 0.f};
  f32x4 accO[4][2];
#pragma unroll
  for (int i = 0; i < 4; ++i) { accO[i][0] = z; accO[i][1] = z; }
  char* Pw = Pl + wave * 8192;
  const int e = 2 * (c & 7);  // even XOR key for 8B-granule swizzle (pair-preserving)

  for (int kt = 0; kt < 16; ++kt) {
    // ---- S^T = K * Q^T : m = s_k (8 tiles), n = s_q (2), k = hd (2 steps) ----
    // K A-frags straight from global; compiler interleaves loads & MFMAs w/ vmcnt(N).
    const char* Kt = Kc + kt * 16384;  // 128 rows * 128 B
    f32x4 sT[8][2];
#pragma unroll
    for (int mt = 0; mt < 8; ++mt) { sT[mt][0] = z; sT[mt][1] = z; }
#pragma unroll
    for (int mt = 0; mt < 8; ++mt) {
      bf16x8 kf0 = *(const bf16x8*)(Kt + mt * 2048);
      bf16x8 kf1 = *(const bf16x8*)(Kt + mt * 2048 + 64);
      sT[mt][0] = MFMA_BF16(kf0, qf[0][0], sT[mt][0]);
      sT[mt][1] = MFMA_BF16(kf0, qf[1][0], sT[mt][1]);
      sT[mt][0] = MFMA_BF16(kf1, qf[0][1], sT[mt][0]);
      sT[mt][1] = MFMA_BF16(kf1, qf[1][1], sT[mt][1]);
    }

    // ---- online softmax over s_k; per-lane state for s_q = nt*16 + c ----
#pragma unroll
    for (int nt = 0; nt < 2; ++nt) {
      // 4-way partial max tree (cuts the 32-deep fmax dependency chain)
      float m0 = sT[0][nt][0], m1 = sT[0][nt][1], m2 = sT[0][nt][2], m3 = sT[0][nt][3];
#pragma unroll
      for (int mt = 1; mt < 8; ++mt) {
        m0 = fmaxf(m0, sT[mt][nt][0]);
        m1 = fmaxf(m1, sT[mt][nt][1]);
        m2 = fmaxf(m2, sT[mt][nt][2]);
        m3 = fmaxf(m3, sT[mt][nt][3]);
      }
      float mx = fmaxf(fmaxf(m0, m1), fmaxf(m2, m3));
      mx = fmaxf(mx, __shfl_xor(mx, 16));
      mx = fmaxf(mx, __shfl_xor(mx, 32));
      float mnew = fmaxf(mM[nt], mx);
      float alpha = fexp2((mM[nt] - mnew) * CSC);  // exp2(-inf)=0 on first tile
      mM[nt] = mnew;
      float mc = mnew * CSC;
      float r0 = 0.f, r1 = 0.f, r2 = 0.f, r3 = 0.f;
#pragma unroll
      for (int mt = 0; mt < 8; ++mt) {
        float p0 = fexp2(sT[mt][nt][0] * CSC - mc);
        float p1 = fexp2(sT[mt][nt][1] * CSC - mc);
        float p2 = fexp2(sT[mt][nt][2] * CSC - mc);
        float p3 = fexp2(sT[mt][nt][3] * CSC - mc);
        sT[mt][nt][0] = p0; sT[mt][nt][1] = p1; sT[mt][nt][2] = p2; sT[mt][nt][3] = p3;
        r0 += p0; r1 += p1; r2 += p2; r3 += p3;
      }
      float rs = (r0 + r1) + (r2 + r3);
      rs += __shfl_xor(rs, 16);
      rs += __shfl_xor(rs, 32);
      lS[nt] = lS[nt] * alpha + rs;
#pragma unroll
      for (int mt = 0; mt < 4; ++mt)
#pragma unroll
        for (int r = 0; r < 4; ++r) accO[mt][nt][r] *= alpha;
      // write P[s_q][s_k] : C-layout regs are consecutive s_k -> packed b64 write
#pragma unroll
      for (int mt = 0; mt < 8; ++mt) {
        union { u16 u[4]; uint2 v; } p;
#pragma unroll
        for (int r = 0; r < 4; ++r) p.u[r] = f2bf(sT[mt][nt][r]);
        int g = 4 * mt + quad;                       // 8B granule along s_k
        *(uint2*)(Pw + (nt * 16 + c) * 256 + (g ^ e) * 8) = p.v;
      }
    }

    // ---- O^T += V^T * P^T : m = hd (4 tiles), n = s_q (2), k = s_k (4 steps) ----
    // V A-frags straight from global: V^T[hd = mt*16+c][s = kt*128 + ks*32 + quad*8 + j]
    const char* Vk = Vc + kt * 256;
#pragma unroll
    for (int ks = 0; ks < 4; ++ks) {
      int g2 = (8 * ks + 2 * quad) ^ e;              // even key -> swizzled pair adjacent
      bf16x8 pf0 = *(const bf16x8*)(Pw + c * 256 + g2 * 8);
      bf16x8 pf1 = *(const bf16x8*)(Pw + (16 + c) * 256 + g2 * 8);
#pragma unroll
      for (int mt = 0; mt < 4; ++mt) {
        bf16x8 vf = *(const bf16x8*)(Vk + mt * 65536 + ks * 64);
        accO[mt][0] = MFMA_BF16(vf, pf0, accO[mt][0]);
        accO[mt][1] = MFMA_BF16(vf, pf1, accO[mt][1]);
      }
    }
  }

  // epilogue: O^T C-layout -> out[b][s][h*64+hd], 4 consecutive hd per reg quad -> float4
#pragma unroll
  for (int nt = 0; nt < 2; ++nt) {
    float inv = 1.f / lS[nt];
    int s = qt * 128 + wave * 32 + nt * 16 + c;
#pragma unroll
    for (int mt = 0; mt < 4; ++mt) {
      float4 o;
      o.x = accO[mt][nt][0] * inv;
      o.y = accO[mt][nt][1] * inv;
      o.z = accO[mt][nt][2] * inv;
      o.w = accO[mt][nt][3] * inv;
      size_t off = ((size_t)(b * SEQ + s)) * DIM + h * HD + mt * 16 + quad * 4;
      *(float4*)(Out + off) = o;
    }
  }
}

extern "C" void kernel_launch(void* const* d_in, const int* in_sizes, int n_in,
                              void* d_out, int out_size, void* d_ws, size_t ws_size,
                              hipStream_t stream) {
  (void)in_sizes; (void)n_in; (void)out_size; (void)ws_size;
  const float* emb = (const float*)d_in[0];
  const float* W = (const float*)d_in[1];
  const float* bias = (const float*)d_in[2];
  float* out = (float*)d_out;
  char* ws = (char*)d_ws;
  // ws layout (bytes): Abf 8 MB | Wt 6 MB | Q 8 MB | K 8 MB | Vt 8 MB  (total ~38 MB)
  u16* Ab = (u16*)ws;
  u16* Wt = (u16*)(ws + 8388608);
  u16* Qd = (u16*)(ws + 14680064);
  u16* Kd = (u16*)(ws + 23068672);
  u16* Vd = (u16*)(ws + 31457280);

  conv_a_kernel<<<4096, 256, 0, stream>>>(emb, Ab);        // 4096*1024 elems / 4 per thread
  conv_wt_kernel<<<1536, 256, 0, stream>>>(W, Wt);         // 3072*128 chunk-threads
  gemm_qkv_kernel<<<768, 256, 0, stream>>>(Ab, Wt, bias, Qd, Kd, Vd);  // 32x24 tiles
  attn_kernel<<<512, 256, 0, stream>>>(Qd, Kd, Vd, out);   // 2*16*16 (b,h,qtile)
}

// Round 5
// 195.780 us; speedup vs baseline: 1.3541x; 1.3541x over previous
//
#include <hip/hip_runtime.h>
#include <stdint.h>

typedef unsigned short u16;
typedef unsigned int u32;
typedef float f32x4 __attribute__((ext_vector_type(4)));
typedef __bf16 bf16x8 __attribute__((ext_vector_type(8)));

#define BS 2
#define SEQ 2048
#define DIM 1024
#define NW3 3072
#define NH 16
#define HD 64

#define MFMA_BF16(a, b, c) __builtin_amdgcn_mfma_f32_16x16x32_bf16((a), (b), (c), 0, 0, 0)

// async global->LDS, 16B per lane; LDS dest must be wave-uniform base + lane*16
#define GLL16(g, l)                                                                \
  __builtin_amdgcn_global_load_lds(                                                \
      (__attribute__((address_space(1))) void*)(void*)(uintptr_t)(g),              \
      (__attribute__((address_space(3))) void*)(l), 16, 0, 0)

__device__ __forceinline__ float fexp2(float x) {
#if defined(__has_builtin)
#if __has_builtin(__builtin_amdgcn_exp2f)
  return __builtin_amdgcn_exp2f(x);
#else
  return exp2f(x);
#endif
#else
  return exp2f(x);
#endif
}

__device__ __forceinline__ u16 f2bf(float x) {
  __bf16 h = (__bf16)x;
  return __builtin_bit_cast(u16, h);
}

// ---------------- fp32 -> bf16 straight convert (embeddings) ----------------
__global__ __launch_bounds__(256) void conv_a_kernel(const float* __restrict__ A,
                                                     u16* __restrict__ O) {
  int i = (blockIdx.x * 256 + threadIdx.x) * 4;
  float4 v = *(const float4*)(A + i);
  union { u16 u[4]; ushort4 v4; } p;
  p.u[0] = f2bf(v.x); p.u[1] = f2bf(v.y); p.u[2] = f2bf(v.z); p.u[3] = f2bf(v.w);
  *(ushort4*)(O + i) = p.v4;
}

// ---------------- W [k][n] fp32 -> Wt [n'][k] bf16 (transposed + head-permuted) --
__global__ __launch_bounds__(256) void conv_wt_kernel(const float* __restrict__ W,
                                                      u16* __restrict__ Wt) {
  int id = blockIdx.x * 256 + threadIdx.x;  // 0 .. 393215
  int kc = id / NW3;                        // 0..127 : chunk of 8 k's
  int n = id - kc * NW3;                    // original column; coalesced reads
  union { u16 u[8]; uint4 v; } p;
#pragma unroll
  for (int i = 0; i < 8; ++i) p.u[i] = f2bf(W[(kc * 8 + i) * NW3 + n]);
  int h = n & 15, hd = (n & 1023) >> 4;
  int np = (n & ~1023) + h * 64 + hd;       // permuted row (head-grouped)
  *(uint4*)(Wt + np * DIM + kc * 8) = p.v;
}

// ---------------- QKV GEMM: [4096x1024]x[1024x3072]+b, bf16 MFMA ----------------
__global__ __launch_bounds__(256) void gemm_qkv_kernel(
    const u16* __restrict__ Ab, const u16* __restrict__ Bt, const float* __restrict__ bias,
    u16* __restrict__ Q, u16* __restrict__ K, u16* __restrict__ Vt) {
  __shared__ __align__(16) u16 Al[128 * 64];
  __shared__ __align__(16) u16 Bl[128 * 64];
  const int t = threadIdx.x;
  const int lane = t & 63, wave = t >> 6;
  const int c = lane & 15, quad = lane >> 4;
  const int tm = blockIdx.x / 24, tn = blockIdx.x - tm * 24;
  const int wm = (wave >> 1) * 64, wn = (wave & 1) * 64;

  const char* Abase = (const char*)(Ab + (size_t)tm * 128 * DIM);
  const char* Bbase = (const char*)(Bt + (size_t)tn * 128 * DIM);

  f32x4 z = {0.f, 0.f, 0.f, 0.f};
  f32x4 acc[4][4];
#pragma unroll
  for (int i = 0; i < 4; ++i)
#pragma unroll
    for (int j = 0; j < 4; ++j) acc[i][j] = z;

  for (int kt = 0; kt < 16; ++kt) {
    __syncthreads();
    const int koff = kt * 128;
#pragma unroll
    for (int r = 0; r < 4; ++r) {
      int l = r * 256 + t;
      int row = l >> 3, pos = l & 7;
      int kc = pos ^ (row & 7);
      GLL16(Abase + row * 2048 + koff + kc * 16, (char*)Al + l * 16);
      GLL16(Bbase + row * 2048 + koff + kc * 16, (char*)Bl + l * 16);
    }
    __syncthreads();
#pragma unroll
    for (int ks = 0; ks < 2; ++ks) {
      bf16x8 af[4], bfr[4];
#pragma unroll
      for (int mt = 0; mt < 4; ++mt) {
        int row = wm + mt * 16 + c;
        int kc = (ks * 4 + quad) ^ (row & 7);
        af[mt] = *(const bf16x8*)((const char*)Al + row * 128 + kc * 16);
      }
#pragma unroll
      for (int nt = 0; nt < 4; ++nt) {
        int row = wn + nt * 16 + c;
        int kc = (ks * 4 + quad) ^ (row & 7);
        bfr[nt] = *(const bf16x8*)((const char*)Bl + row * 128 + kc * 16);
      }
#pragma unroll
      for (int mt = 0; mt < 4; ++mt)
#pragma unroll
        for (int nt = 0; nt < 4; ++nt)
          acc[mt][nt] = MFMA_BF16(af[mt], bfr[nt], acc[mt][nt]);
    }
  }

  // Epilogue: C/D layout col = lane&15, row = quad*4 + reg (m89-verified).
#pragma unroll
  for (int nt = 0; nt < 4; ++nt) {
    int np = tn * 128 + wn + nt * 16 + c;
    int which = np >> 10;
    int rem = np & 1023;
    int h = rem >> 6, hd = rem & 63;
    float bv = bias[(np & ~1023) + hd * 16 + h];  // bias in ORIGINAL column order
#pragma unroll
    for (int mt = 0; mt < 4; ++mt) {
      int mbase = tm * 128 + wm + mt * 16 + quad * 4;
      int bI = mbase >> 11;
      int s0 = mbase & 2047;
      if (which == 2) {
        union { u16 u[4]; uint2 v; } p;
#pragma unroll
        for (int r = 0; r < 4; ++r) p.u[r] = f2bf(acc[mt][nt][r] + bv);
        *(uint2*)(Vt + ((size_t)(bI * NH + h) * HD + hd) * SEQ + s0) = p.v;  // [b,h,hd,s]
      } else {
        u16* dst = (which == 0) ? Q : K;
#pragma unroll
        for (int r = 0; r < 4; ++r)
          dst[((size_t)(bI * NH + h) * SEQ + (s0 + r)) * HD + hd] = f2bf(acc[mt][nt][r] + bv);
      }
    }
  }
}

// ---------------- Flash attention v4: LDS-staged (R1 skeleton), 2x parallelism,
// P transform via cross-lane shuffles (no P LDS, no bank conflicts) ----------------
// Block = (b, h, 64 q rows), 4 waves x 16 q rows; grid 1024 = 4 blocks/CU.
// LDS = K tile 16 KB + V^T tile 16 KB = 32 KB.
// S^T = K*Q^T (m=s_k, n=s_q): C-frag lane (c,quad) reg r holds
//   S^T[s_k = mt*16 + quad*4 + r][s_q = c].
// PV B-frag needs P^T[s_k = ks*32 + quad*8 + j][s_q = c]: a pure permutation
// among the 4 lanes sharing c -> 8 shuffles + 4 selects per ks (derivation:
// source quad = (quad&1)*2 + (W>>1), source reg-pair word = W&1, source
// register = pk[2ks + (quad>>1)]).
#define CSC 0.18033688011112042f  // 0.125 * log2(e)

__global__ __launch_bounds__(256, 4) void attn_kernel(
    const u16* __restrict__ Q, const u16* __restrict__ K,
    const u16* __restrict__ Vt, float* __restrict__ Out) {
  __shared__ __align__(16) u16 Kl[128 * 64];   // 16 KB (also Q staging)
  __shared__ __align__(16) u16 Vl[64 * 128];   // 16 KB  V^T tile [hd][s_k]
  const int t = threadIdx.x;
  const int lane = t & 63, wave = t >> 6;
  const int c = lane & 15, quad = lane >> 4;
  const int qt = blockIdx.x & 31, bh = blockIdx.x >> 5;
  const int h = bh & 15, b = bh >> 4;

  const u16* Qb = Q + ((size_t)bh * SEQ + qt * 64) * HD;
  const char* Kb = (const char*)(K + (size_t)bh * SEQ * HD);
  const char* Vb = (const char*)(Vt + (size_t)bh * HD * SEQ);

  // stage Q tile (64 rows x 128 B = 8 KB) through Kl
#pragma unroll
  for (int r = 0; r < 2; ++r) {
    int l = r * 256 + t;
    int row = l >> 3, pos = l & 7;
    int kc = pos ^ (row & 7);
    GLL16((const char*)Qb + row * 128 + kc * 16, (char*)Kl + l * 16);
  }
  __syncthreads();
  bf16x8 qf[2];
#pragma unroll
  for (int ks = 0; ks < 2; ++ks) {
    int row = wave * 16 + c;
    int kc = (ks * 4 + quad) ^ (row & 7);
    qf[ks] = *(const bf16x8*)((const char*)Kl + row * 128 + kc * 16);
  }

  float mM = -__builtin_inff();
  float lS = 0.f;
  f32x4 z = {0.f, 0.f, 0.f, 0.f};
  f32x4 accO[4];
#pragma unroll
  for (int i = 0; i < 4; ++i) accO[i] = z;

  const int sl0 = c + 16 * ((quad & 1) * 2);  // shuffle source lanes (see header)
  const int sl1 = sl0 + 16;
  const bool hi = quad >= 2;

  for (int kt = 0; kt < 16; ++kt) {
    __syncthreads();  // waves done reading Kl/Vl (kt=0: done reading qf)
    const char* Ktb = Kb + (size_t)kt * 16384;  // 128 rows * 128 B
    const char* Vtb = Vb + (size_t)kt * 256;    // 128 cols * 2 B into 4096 B rows
#pragma unroll
    for (int r = 0; r < 4; ++r) {
      int l = r * 256 + t;
      { int row = l >> 3, pos = l & 7; int kc = pos ^ (row & 7);
        GLL16(Ktb + row * 128 + kc * 16, (char*)Kl + l * 16); }
      { int row = l >> 4, pos = l & 15; int kc = pos ^ (row & 15);
        GLL16(Vtb + row * 4096 + kc * 16, (char*)Vl + l * 16); }
    }
    __syncthreads();  // GLL drain: K/V visible

    // ---- S^T = K * Q^T : m = s_k (8 tiles of 16), n = s_q (16), k = hd (2 steps)
    f32x4 sT[8];
#pragma unroll
    for (int mt = 0; mt < 8; ++mt) {
      sT[mt] = z;
#pragma unroll
      for (int ks = 0; ks < 2; ++ks) {
        int row = mt * 16 + c;
        int kc = (ks * 4 + quad) ^ (row & 7);
        bf16x8 kf = *(const bf16x8*)((const char*)Kl + row * 128 + kc * 16);
        sT[mt] = MFMA_BF16(kf, qf[ks], sT[mt]);
      }
    }

    // ---- online softmax over s_k (per-lane state for s_q = c) ----
    float m0 = sT[0][0], m1 = sT[0][1], m2 = sT[0][2], m3 = sT[0][3];
#pragma unroll
    for (int mt = 1; mt < 8; ++mt) {
      m0 = fmaxf(m0, sT[mt][0]);
      m1 = fmaxf(m1, sT[mt][1]);
      m2 = fmaxf(m2, sT[mt][2]);
      m3 = fmaxf(m3, sT[mt][3]);
    }
    float mx = fmaxf(fmaxf(m0, m1), fmaxf(m2, m3));
    mx = fmaxf(mx, __shfl_xor(mx, 16));
    mx = fmaxf(mx, __shfl_xor(mx, 32));
    float mnew = fmaxf(mM, mx);
    float alpha = fexp2((mM - mnew) * CSC);  // exp2(-inf)=0 on first tile
    mM = mnew;
    float mc = mnew * CSC;
    float r0 = 0.f, r1 = 0.f, r2 = 0.f, r3 = 0.f;
#pragma unroll
    for (int mt = 0; mt < 8; ++mt) {
      float p0 = fexp2(sT[mt][0] * CSC - mc);
      float p1 = fexp2(sT[mt][1] * CSC - mc);
      float p2 = fexp2(sT[mt][2] * CSC - mc);
      float p3 = fexp2(sT[mt][3] * CSC - mc);
      sT[mt][0] = p0; sT[mt][1] = p1; sT[mt][2] = p2; sT[mt][3] = p3;
      r0 += p0; r1 += p1; r2 += p2; r3 += p3;
    }
    float rs = (r0 + r1) + (r2 + r3);
    rs += __shfl_xor(rs, 16);
    rs += __shfl_xor(rs, 32);
    lS = lS * alpha + rs;
#pragma unroll
    for (int mt = 0; mt < 4; ++mt)
#pragma unroll
      for (int r = 0; r < 4; ++r) accO[mt][r] *= alpha;

    // pack P rows to bf16 pairs: pk[mt][w] holds s_k = mt*16 + quad*4 + 2w + {0,1}
    u32 pk[8][2];
#pragma unroll
    for (int mt = 0; mt < 8; ++mt) {
      pk[mt][0] = (u32)f2bf(sT[mt][0]) | ((u32)f2bf(sT[mt][1]) << 16);
      pk[mt][1] = (u32)f2bf(sT[mt][2]) | ((u32)f2bf(sT[mt][3]) << 16);
    }

    // ---- O^T += V^T * P^T : m = hd (4 tiles), k = s_k (4 steps of 32) ----
    const char* Vkl = (const char*)Vl;
#pragma unroll
    for (int ks = 0; ks < 4; ++ks) {
      // B-frag via cross-lane shuffles (mapping verified in header comment)
      u32 a0 = __shfl(pk[2 * ks][0], sl0),     a1 = __shfl(pk[2 * ks][1], sl0);
      u32 a2 = __shfl(pk[2 * ks][0], sl1),     a3 = __shfl(pk[2 * ks][1], sl1);
      u32 b0 = __shfl(pk[2 * ks + 1][0], sl0), b1 = __shfl(pk[2 * ks + 1][1], sl0);
      u32 b2 = __shfl(pk[2 * ks + 1][0], sl1), b3 = __shfl(pk[2 * ks + 1][1], sl1);
      uint4 wv;
      wv.x = hi ? b0 : a0; wv.y = hi ? b1 : a1;
      wv.z = hi ? b2 : a2; wv.w = hi ? b3 : a3;
      bf16x8 pf = __builtin_bit_cast(bf16x8, wv);
#pragma unroll
      for (int mt = 0; mt < 4; ++mt) {
        int row = mt * 16 + c;
        int kc = (ks * 4 + quad) ^ (row & 15);
        bf16x8 vf = *(const bf16x8*)(Vkl + row * 256 + kc * 16);
        accO[mt] = MFMA_BF16(vf, pf, accO[mt]);
      }
    }
  }

  // epilogue: O^T C-layout -> out[b][s][h*64+hd], float4 per (mt,quad)
  float inv = 1.f / lS;
  int s = qt * 64 + wave * 16 + c;
#pragma unroll
  for (int mt = 0; mt < 4; ++mt) {
    float4 o;
    o.x = accO[mt][0] * inv;
    o.y = accO[mt][1] * inv;
    o.z = accO[mt][2] * inv;
    o.w = accO[mt][3] * inv;
    size_t off = ((size_t)(b * SEQ + s)) * DIM + h * HD + mt * 16 + quad * 4;
    *(float4*)(Out + off) = o;
  }
}

extern "C" void kernel_launch(void* const* d_in, const int* in_sizes, int n_in,
                              void* d_out, int out_size, void* d_ws, size_t ws_size,
                              hipStream_t stream) {
  (void)in_sizes; (void)n_in; (void)out_size; (void)ws_size;
  const float* emb = (const float*)d_in[0];
  const float* W = (const float*)d_in[1];
  const float* bias = (const float*)d_in[2];
  float* out = (float*)d_out;
  char* ws = (char*)d_ws;
  // ws layout (bytes): Abf 8 MB | Wt 6 MB | Q 8 MB | K 8 MB | Vt 8 MB  (total ~38 MB)
  u16* Ab = (u16*)ws;
  u16* Wt = (u16*)(ws + 8388608);
  u16* Qd = (u16*)(ws + 14680064);
  u16* Kd = (u16*)(ws + 23068672);
  u16* Vd = (u16*)(ws + 31457280);

  conv_a_kernel<<<4096, 256, 0, stream>>>(emb, Ab);
  conv_wt_kernel<<<1536, 256, 0, stream>>>(W, Wt);
  gemm_qkv_kernel<<<768, 256, 0, stream>>>(Ab, Wt, bias, Qd, Kd, Vd);
  attn_kernel<<<1024, 256, 0, stream>>>(Qd, Kd, Vd, out);  // (b,h) x 32 q-tiles of 64
}